// Round 6
// baseline (926.015 us; speedup 1.0000x reference)
//
#include <hip/hip_runtime.h>
#include <stdint.h>

// Problem constants: B=64, T=64, C=4096, H=64, hd=64, rank=1, scale=0.125
#define M_TOK   4096      // B*T
#define C_DIM   4096
#define N_QKV   12288
#define KD      4096      // K for both GEMMs
#define NT2     32        // (KD/64)/2 iterations, 2 K-tiles each

typedef __bf16 bf16x8 __attribute__((ext_vector_type(8)));
typedef float  f32x4  __attribute__((ext_vector_type(4)));
typedef unsigned short ushort8 __attribute__((ext_vector_type(8)));

__device__ __forceinline__ unsigned short f2bf(float f) {
  unsigned int u = __builtin_bit_cast(unsigned int, f);
  u = (u + 0x7FFFu + ((u >> 16) & 1u)) >> 16;   // RNE
  return (unsigned short)u;
}

// ---------------- fp32 -> bf16 conversion (16B out per thread) ----------------
__global__ __launch_bounds__(256) void cvt_f32_bf16(const float* __restrict__ in,
                                                    unsigned short* __restrict__ out,
                                                    int n16) {  // n16 = elems/8
  int idx = blockIdx.x * 256 + threadIdx.x;
  if (idx >= n16) return;
  const float4* p = (const float4*)in;
  float4 a = p[idx * 2], b = p[idx * 2 + 1];
  uint4 r;
  r.x = (unsigned)f2bf(a.x) | ((unsigned)f2bf(a.y) << 16);
  r.y = (unsigned)f2bf(a.z) | ((unsigned)f2bf(a.w) << 16);
  r.z = (unsigned)f2bf(b.x) | ((unsigned)f2bf(b.y) << 16);
  r.w = (unsigned)f2bf(b.z) | ((unsigned)f2bf(b.w) << 16);
  ((uint4*)out)[idx] = r;
}

#define GLLDS(gp, lp) \
  __builtin_amdgcn_global_load_lds((const __attribute__((address_space(1))) unsigned int*)(gp), \
                                   (__attribute__((address_space(3))) unsigned int*)(lp), 16, 0, 0)

// =====================================================================
// 256x256 bf16 NT GEMM, K=4096. 512 thr = 8 waves (2M x 4N), BK=64,
// LDS 128 KiB double buffer. Tile t -> buf[t&1].
//
// BALANCED LOOKAHEAD SCHEDULE (this round): reads spread 8/4/4/8 across
// the 4 phases of a tile, every quad consumes regs read ONE PHASE EARLIER,
// counted lgkm waits (= own phase's issue count), ONE barrier per phase.
// A-banks swap roles per tile (A_lo(t)=A[t&1], A_hi(t)=A[1-(t&1)]):
// P1 fills off-bank with A_hi; P4 refills the SAME bank with next A_lo
// (A_hi last use is P3) -> no third bank, VGPR unchanged (~128, 2 w/SIMD).
//
// Per tile t (buf b=t&1; quads Q00,Q10,Q11,Q01):
//  P1: stage S1(t+1)->b^1 | rd A_hi(8)<-b.mh1      | lgkm(8)  | Q00(A_lo,Bl) | bar
//  P2: stage S0(t+2)->b   | rd B_hi(4)<-b.nhf1     | lgkm(4)  | Q10(A_hi,Bl) | vm6 bar
//  P3: stage T0(t+2)->b   | rd Bl'(4)<-b^1.nhf0    | lgkm(4)  | Q11(A_hi,Bh) | bar
//  P4: stage T1(t+2)->b   | rd A_lo'(8)<-b^1.mh0   | lgkm(8)  | Q01(A_lo,Bh) | vm6 bar
// Counted-wait proof (per-wave in-order ds returns): each phase's wait
// leaves exactly its own issue outstanding -> prev phase's group retired.
// WAR: each staged region's last LDS-read retires before that wave's prior
// MFMA -> before the barrier preceding the stage (checked all 4 regions x
// both bufs). RAW: vm6 at P2 retires S0(t+1)+T0(t+1) (feeds P3/P4 reads);
// vm6 at P4 retires T1(t+1)+S1(t+1) (feeds next P1/P2 reads); 6 loads
// always in flight (T4, never drained in-loop). Tail stages clamp to 63
// (dead data into dead regions; dead reads are race-free via same vm6).
// =====================================================================

#define STAGE_A(buf, hf, tau) do {                                         \
    const unsigned short* g_ = Ag + (size_t)((hf) * 64) * KD + (tau) * 64; \
    unsigned short* d_ = As + (buf) * 16384 + (hf) * 8192 + t * 8;         \
    GLLDS(g_, d_);                                                         \
    GLLDS(g_ + (size_t)128 * KD, d_ + 4096);                               \
  } while (0)

#define STAGE_B(buf, nhf, tau) do {                                         \
    const unsigned short* g_ = Bg + (size_t)((nhf) * 32) * KD + (tau) * 64; \
    unsigned short* d_ = Bs + (buf) * 16384 + (nhf) * 8192 + t * 8;         \
    GLLDS(g_, d_);                                                          \
    GLLDS(g_ + (size_t)128 * KD, d_ + 4096);                                \
  } while (0)

// A-frag fill (8 x ds_read_b128) into explicit bank, kk-major
#define RD_A(buf, mh, bank) do {                                                  \
    const unsigned short* pa_ = As + (buf) * 16384 + (mh) * 8192 + wm * 4096 + lr * 64; \
    bank[0][0] = *(const bf16x8*)(pa_ + 0 * 1024 + ck0);                          \
    bank[0][1] = *(const bf16x8*)(pa_ + 1 * 1024 + ck0);                          \
    bank[0][2] = *(const bf16x8*)(pa_ + 2 * 1024 + ck0);                          \
    bank[0][3] = *(const bf16x8*)(pa_ + 3 * 1024 + ck0);                          \
    bank[1][0] = *(const bf16x8*)(pa_ + 0 * 1024 + ck1);                          \
    bank[1][1] = *(const bf16x8*)(pa_ + 1 * 1024 + ck1);                          \
    bank[1][2] = *(const bf16x8*)(pa_ + 2 * 1024 + ck1);                          \
    bank[1][3] = *(const bf16x8*)(pa_ + 3 * 1024 + ck1);                          \
  } while (0)

// B-frag fill (4 x ds_read_b128)
#define RD_B(buf, nhf, dst) do {                                                  \
    const unsigned short* pb_ = Bs + (buf) * 16384 + (nhf) * 8192 + wn * 2048 + lr * 64; \
    dst[0][0] = *(const bf16x8*)(pb_ + 0 * 1024 + ck0);                           \
    dst[0][1] = *(const bf16x8*)(pb_ + 1 * 1024 + ck0);                           \
    dst[1][0] = *(const bf16x8*)(pb_ + 0 * 1024 + ck1);                           \
    dst[1][1] = *(const bf16x8*)(pb_ + 1 * 1024 + ck1);                           \
  } while (0)

#define QUAD_(mh, nhf, abank, bsrc) do {                                          \
    __builtin_amdgcn_s_setprio(1);                                                \
    _Pragma("unroll") for (int kk_ = 0; kk_ < 2; ++kk_)                           \
    _Pragma("unroll") for (int mt_ = 0; mt_ < 4; ++mt_)                           \
    _Pragma("unroll") for (int nt_ = 0; nt_ < 2; ++nt_)                           \
      acc[mh][nhf][mt_][nt_] = __builtin_amdgcn_mfma_f32_16x16x32_bf16(           \
          abank[kk_][mt_], bsrc[kk_][nt_], acc[mh][nhf][mt_][nt_], 0, 0, 0);      \
    __builtin_amdgcn_s_setprio(0);                                                \
  } while (0)

#define SB_()   __builtin_amdgcn_sched_barrier(0)
#define BAR_()  do { asm volatile("" ::: "memory"); __builtin_amdgcn_s_barrier(); \
                     asm volatile("" ::: "memory"); } while (0)
// counted lgkm: waits only up to this phase's own issue -> prev group retired
#define LGKM8_() do { asm volatile("s_waitcnt lgkmcnt(8)" ::: "memory"); SB_(); } while (0)
#define LGKM4_() do { asm volatile("s_waitcnt lgkmcnt(4)" ::: "memory"); SB_(); } while (0)
#define VM6_()   asm volatile("s_waitcnt vmcnt(6)" ::: "memory")

template <int OUT_BF16>
__global__ __launch_bounds__(512, 2) void gemm256(const unsigned short* __restrict__ A,
                                                  const unsigned short* __restrict__ B,
                                                  const float* __restrict__ bias,
                                                  void* __restrict__ Cptr,
                                                  int N) {
  // 128 KiB static LDS — 1 block/CU, 8 waves
  __shared__ __align__(16) unsigned short As[32768];
  __shared__ __align__(16) unsigned short Bs[32768];

  const int t   = threadIdx.x;
  const int nwg = gridDim.x;
  const int bid = blockIdx.x;
  // T1: bijective XCD swizzle (nwg % 8 == 0 for all our launches)
  const int wg  = (bid & 7) * (nwg >> 3) + (bid >> 3);
  const int bm  = wg & 15;             // M/256 == 16 always; bn-major chunks
  const int bn  = wg >> 4;             // -> per-XCD B-panel reuse in its L2

  const int w  = t >> 6, l = t & 63;
  const int wm = w >> 2, wn = w & 3;   // 2M x 4N wave grid
  const int lr = l & 15, lq = l >> 4;
  const int ck0 = (lq ^ (lr & 7)) * 8; // un-swizzled read chunk, kk=0
  const int ck1 = ck0 ^ 32;            // kk=1

  // staging: thread t covers row r8=t>>3, global chunk pre-swizzled so
  // LDS(row,c) = global chunk c^(row&7)  [G21: both sides]
  const int r8  = t >> 3;
  const int kcs = ((t & 7) ^ (r8 & 7)) * 8;
  const unsigned short* Ag = A + (size_t)(bm * 256 + r8) * KD + kcs;
  const unsigned short* Bg = B + (size_t)(bn * 256 + ((t >> 8) << 6) + (r8 & 31)) * KD + kcs;

  f32x4 acc[2][2][4][2] = {};          // [mh][nhf][mt][nt]
  bf16x8 A0[2][4], A1[2][4], Bl[2][2], Bh[2][2];

  // prologue: tile0 {S0,T0,T1,S1} + tile1 {S0,T0,T1} (14 loads);
  // vm6 retires tile0's 8; outstanding = tile1's 6 (steady-state pattern)
  STAGE_A(0, 0, 0); STAGE_B(0, 0, 0); STAGE_B(0, 1, 0); STAGE_A(0, 1, 0);
  STAGE_A(1, 0, 1); STAGE_B(1, 0, 1); STAGE_B(1, 1, 1);
  VM6_();
  BAR_();
  // pre-reads for P1(0): A_lo(0)->A0, B_lo(0)->Bl (retired by P1's lgkm(8))
  RD_A(0, 0, A0); RD_B(0, 0, Bl);

#pragma unroll 1
  for (int i = 0; i < NT2; ++i) {
    const int tS1e = 2 * i + 1;                          // <= 63 always
    const int te2  = (2 * i + 2 < 64) ? 2 * i + 2 : 63;  // clamp: dead stages
    const int to2  = (2 * i + 3 < 64) ? 2 * i + 3 : 63;

    // ======== even tile 2i (buf0): A_lo=A0, A_hi=A1 ========
    // P1
    STAGE_A(1, 1, tS1e);       // S1(2i+1) -> buf1
    RD_A(0, 1, A1);            // A_hi
    LGKM8_();
    QUAD_(0, 0, A0, Bl);
    BAR_();
    // P2
    STAGE_A(0, 0, te2);        // S0(2i+2) -> buf0
    RD_B(0, 1, Bh);            // B_hi
    LGKM4_();
    QUAD_(1, 0, A1, Bl);
    VM6_();
    BAR_();
    // P3
    STAGE_B(0, 0, te2);        // T0(2i+2) -> buf0
    RD_B(1, 0, Bl);            // B_lo(2i+1) from buf1
    LGKM4_();
    QUAD_(1, 1, A1, Bh);
    BAR_();
    // P4
    STAGE_B(0, 1, te2);        // T1(2i+2) -> buf0
    RD_A(1, 0, A1);            // A_lo(2i+1) -> bank A1 (A_hi done at P3)
    LGKM8_();
    QUAD_(0, 1, A0, Bh);
    VM6_();
    BAR_();

    // ======== odd tile 2i+1 (buf1): A_lo=A1, A_hi=A0 ========
    // P1
    STAGE_A(0, 1, te2);        // S1(2i+2) -> buf0
    RD_A(1, 1, A0);            // A_hi from buf1 mh1
    LGKM8_();
    QUAD_(0, 0, A1, Bl);
    BAR_();
    // P2
    STAGE_A(1, 0, to2);        // S0(2i+3) -> buf1
    RD_B(1, 1, Bh);
    LGKM4_();
    QUAD_(1, 0, A0, Bl);
    VM6_();
    BAR_();
    // P3
    STAGE_B(1, 0, to2);        // T0(2i+3) -> buf1
    RD_B(0, 0, Bl);            // B_lo(2i+2) from buf0
    LGKM4_();
    QUAD_(1, 1, A0, Bh);
    BAR_();
    // P4
    STAGE_B(1, 1, to2);        // T1(2i+3) -> buf1
    RD_A(0, 0, A0);            // A_lo(2i+2) -> bank A0
    LGKM8_();
    QUAD_(0, 1, A1, Bh);
    VM6_();
    BAR_();
  }

  // drain in-flight LDS-DMA before waves exit
  asm volatile("s_waitcnt vmcnt(0) lgkmcnt(0)" ::: "memory");

  // epilogue: C/D layout col=lane&15, row=(lane>>4)*4+reg
  const int row0 = bm * 256 + wm * 128 + lq * 4;
  const int col0 = bn * 256 + wn * 64 + lr;
#pragma unroll
  for (int nhf = 0; nhf < 2; ++nhf)
#pragma unroll
    for (int nt = 0; nt < 2; ++nt) {
      const int col = col0 + nhf * 32 + nt * 16;
      const float bv = bias[col];
#pragma unroll
      for (int mh = 0; mh < 2; ++mh)
#pragma unroll
        for (int mt = 0; mt < 4; ++mt) {
          const int row = row0 + mh * 64 + mt * 16;
#pragma unroll
          for (int rg = 0; rg < 4; ++rg) {
            float v = acc[mh][nhf][mt][nt][rg] + bv;
            if (OUT_BF16)
              ((unsigned short*)Cptr)[(size_t)(row + rg) * N + col] = f2bf(v);
            else
              ((float*)Cptr)[(size_t)(row + rg) * N + col] = v;
          }
        }
    }
}

// ---------------- head-mixing attention, MFMA, one WAVE per (b,t) -------------
#define AST 72   // padded LDS row stride (elements)

__global__ __launch_bounds__(64) void attn_mfma(const unsigned short* __restrict__ qkv,
                                                unsigned short* __restrict__ y) {
  __shared__ __align__(16) unsigned short Ks[64 * AST];   // K, later P
  __shared__ __align__(16) unsigned short Vs[64 * AST];
  const int l  = threadIdx.x;
  const int lr = l & 15;
  const int lq = l >> 4;
  const size_t base = (size_t)blockIdx.x * 12288;

  // ---- stage K,V (coalesced 16B loads, padded LDS rows) ----
  {
    const int jr = l >> 3;          // 0..7
    const int cc = (l & 7) * 8;     // col chunk (elements)
#pragma unroll
    for (int c = 0; c < 8; ++c) {
      const int j = c * 8 + jr;
      *(uint4*)(Ks + j * AST + cc) = *(const uint4*)(qkv + base + 4096 + (size_t)j * 64 + cc);
      *(uint4*)(Vs + j * AST + cc) = *(const uint4*)(qkv + base + 8192 + (size_t)j * 64 + cc);
    }
  }

  // ---- Q A-frags direct from global ----
  bf16x8 aq[4][2];
#pragma unroll
  for (int it = 0; it < 4; ++it)
#pragma unroll
    for (int kk = 0; kk < 2; ++kk)
      aq[it][kk] = *(const bf16x8*)(qkv + base + (size_t)(it * 16 + lr) * 64 + kk * 32 + lq * 8);

  __syncthreads();

  // ---- S = Q K^T ----
  f32x4 acc[4][4] = {};
#pragma unroll
  for (int kk = 0; kk < 2; ++kk) {
    bf16x8 bk[4];
#pragma unroll
    for (int jt = 0; jt < 4; ++jt)
      bk[jt] = *(const bf16x8*)(Ks + (jt * 16 + lr) * AST + kk * 32 + lq * 8);
#pragma unroll
    for (int it = 0; it < 4; ++it)
#pragma unroll
      for (int jt = 0; jt < 4; ++jt)
        acc[it][jt] = __builtin_amdgcn_mfma_f32_16x16x32_bf16(aq[it][kk], bk[jt], acc[it][jt], 0, 0, 0);
  }

  // ---- mask + softmax in-register ----
#pragma unroll
  for (int it = 0; it < 4; ++it) {
#pragma unroll
    for (int rg = 0; rg < 4; ++rg) {
      const int row = it * 16 + lq * 4 + rg;
      float mx = -1e30f;
#pragma unroll
      for (int jt = 0; jt < 4; ++jt) {
        const int col = jt * 16 + lr;
        float s = acc[it][jt][rg] * 0.125f;
        s = (col <= row) ? s : -1e30f;
        acc[it][jt][rg] = s;
        mx = fmaxf(mx, s);
      }
#pragma unroll
      for (int d = 1; d < 16; d <<= 1)
        mx = fmaxf(mx, __shfl_xor(mx, d));
      float sum = 0.f;
#pragma unroll
      for (int jt = 0; jt < 4; ++jt) {
        float e = __expf(acc[it][jt][rg] - mx);
        acc[it][jt][rg] = e;
        sum += e;
      }
#pragma unroll
      for (int d = 1; d < 16; d <<= 1)
        sum += __shfl_xor(sum, d);
      const float inv = 1.f / sum;
#pragma unroll
      for (int jt = 0; jt < 4; ++jt)
        acc[it][jt][rg] *= inv;
    }
  }

  // ---- P -> LDS (bf16), reusing K slab ----
#pragma unroll
  for (int it = 0; it < 4; ++it)
#pragma unroll
    for (int rg = 0; rg < 4; ++rg) {
      const int row = it * 16 + lq * 4 + rg;
#pragma unroll
      for (int jt = 0; jt < 4; ++jt)
        Ks[row * AST + jt * 16 + lr] = f2bf(acc[it][jt][rg]);
    }
  __syncthreads();

  // ---- Y = P V ----
  f32x4 out[4][4] = {};
#pragma unroll
  for (int kk = 0; kk < 2; ++kk) {
    bf16x8 ap[4];
#pragma unroll
    for (int it = 0; it < 4; ++it)
      ap[it] = *(const bf16x8*)(Ks + (it * 16 + lr) * AST + kk * 32 + lq * 8);
#pragma unroll
    for (int dt = 0; dt < 4; ++dt) {
      ushort8 vt;
#pragma unroll
      for (int jj = 0; jj < 8; ++jj)
        vt[jj] = Vs[(kk * 32 + lq * 8 + jj) * AST + dt * 16 + lr];
      const bf16x8 bv = __builtin_bit_cast(bf16x8, vt);
#pragma unroll
      for (int it = 0; it < 4; ++it)
        out[it][dt] = __builtin_amdgcn_mfma_f32_16x16x32_bf16(ap[it], bv, out[it][dt], 0, 0, 0);
    }
  }

  // ---- epilogue: y[bt][i*64+d] bf16 ----
  unsigned short* yrow = y + (size_t)blockIdx.x * 4096;
#pragma unroll
  for (int it = 0; it < 4; ++it)
#pragma unroll
    for (int rg = 0; rg < 4; ++rg) {
      const int i = it * 16 + lq * 4 + rg;
#pragma unroll
      for (int dt = 0; dt < 4; ++dt)
        yrow[i * 64 + dt * 16 + lr] = f2bf(out[it][dt][rg]);
    }
}

// ---------------- launch ------------------------------------------------------
extern "C" void kernel_launch(void* const* d_in, const int* in_sizes, int n_in,
                              void* d_out, int out_size, void* d_ws, size_t ws_size,
                              hipStream_t stream) {
  const float* x  = (const float*)d_in[0];   // (64,64,4096)
  const float* Wa = (const float*)d_in[1];   // (12288,4096)
  const float* ba = (const float*)d_in[2];   // (12288)
  const float* Wp = (const float*)d_in[3];   // (4096,4096)
  const float* bp = (const float*)d_in[4];   // (4096)
  float* out = (float*)d_out;                // (64,64,4096) fp32

  // workspace layout (ushort elems), regions reused across phases:
  unsigned short* regA = (unsigned short*)d_ws;                 // 33.5 MB
  unsigned short* regB = regA + (size_t)16777216;               // 100.7 MB
  unsigned short* regC = regB + (size_t)50331648;               // 100.7 MB
  unsigned short* xb   = regA;
  unsigned short* Wab  = regB;
  unsigned short* qkvb = regC;
  unsigned short* Wpb  = regA;   // reuse after GEMM1 consumed xb
  unsigned short* yb   = regB;   // reuse after GEMM1 consumed Wab

  cvt_f32_bf16<<<(16777216 / 8) / 256, 256, 0, stream>>>(x, xb, 16777216 / 8);
  cvt_f32_bf16<<<(50331648 / 8) / 256, 256, 0, stream>>>(Wa, Wab, 50331648 / 8);

  // qkv = x @ Wa^T + ba   (M=4096, N=12288, K=4096), bf16 out; grid 768
  gemm256<1><<<dim3((M_TOK / 256) * (N_QKV / 256)), dim3(512), 0, stream>>>(
      xb, Wab, ba, (void*)qkvb, N_QKV);

  cvt_f32_bf16<<<(16777216 / 8) / 256, 256, 0, stream>>>(Wp, Wpb, 16777216 / 8);

  attn_mfma<<<M_TOK, 64, 0, stream>>>(qkvb, yb);

  // out = y @ Wp^T + bp   (M=4096, N=4096, K=4096), fp32 out; grid 256
  gemm256<0><<<dim3((M_TOK / 256) * (C_DIM / 256)), dim3(512), 0, stream>>>(
      yb, Wpb, bp, (void*)out, C_DIM);
}